// Round 5
// baseline (306.339 us; speedup 1.0000x reference)
//
#include <hip/hip_runtime.h>

// Inputs/outputs FLOAT32 per the reference. bf16 internally for MFMA (raw u16).
// r12: proj_fused occupancy fix. r8's 128x128 tile needs 64KB LDS -> 2
// blocks/CU = 2 waves/SIMD; counters (MfmaUtil 25 / VALU 31 / Occ 17.5) show
// ~2/3 of cycles stalled at the barrier+DMA drain with nothing to fill them.
// r12: 64x128 tile (F 64x32 f32 + H/L 128x32 bf16 = 24KB/buf = 48KB dbuf)
// -> 3 blocks/CU (+50% wave slots). Job 2 carves the same 48KB as F 128 rows
// (B-side x) + H 64 rows (A-side weights). Grid (512,3); xcd = tile%8 = n&7
// keeps weight/x-panel L2 clustering. Per-element math bit-identical to r8.
typedef unsigned short u16;
typedef unsigned int u32;
typedef __attribute__((ext_vector_type(8))) short short8;   // MFMA A/B frag
typedef __attribute__((ext_vector_type(4))) float f32x4;    // MFMA C/D frag

__device__ inline u16 f32_to_bf16(float f) {          // RNE (cold paths only)
  u32 u = __float_as_uint(f);
  u += 0x7fffu + ((u >> 16) & 1u);
  return (u16)(u >> 16);
}
__device__ inline float bf16_to_f32(u16 s) {
  return __uint_as_float(((u32)s) << 16);
}

#if __has_builtin(__builtin_amdgcn_exp2f)
#define EXP2F(x) __builtin_amdgcn_exp2f(x)
#else
#define EXP2F(x) exp2f(x)
#endif

// async 16B global->LDS DMA (dest = wave-uniform LDS base + lane*16)
__device__ inline void dma16(const void* gp, void* lp) {
  __builtin_amdgcn_global_load_lds(
      (const __attribute__((address_space(1))) u32*)gp,
      (__attribute__((address_space(3))) u32*)lp, 16, 0, 0);
}

// pack top-16 of two f32 words: out = (hi16(b)<<16) | hi16(a)
__device__ inline u32 pack_hi16(u32 a, u32 b) {
  return __builtin_amdgcn_perm(b, a, 0x07060302u);
}
// 8 f32 -> bf16x8 via truncation
__device__ inline uint4 pack_bf16_8(const uint4 a, const uint4 b) {
  uint4 r;
  r.x = pack_hi16(a.x, a.y);
  r.y = pack_hi16(a.z, a.w);
  r.z = pack_hi16(b.x, b.y);
  r.w = pack_hi16(b.z, b.w);
  return r;
}
// 8 f32 -> hi/lo bf16 planes. hi=trunc; lo=trunc(v-hi) (v-hi exact, Sterbenz).
__device__ inline void split8(const uint4 a, const uint4 b, uint4& hi, uint4& lo) {
  u32 u[8] = {a.x, a.y, a.z, a.w, b.x, b.y, b.z, b.w};
  u32 l[8];
#pragma unroll
  for (int j = 0; j < 8; ++j)
    l[j] = __float_as_uint(__uint_as_float(u[j]) - __uint_as_float(u[j] & 0xffff0000u));
  hi.x = pack_hi16(u[0], u[1]); hi.y = pack_hi16(u[2], u[3]);
  hi.z = pack_hi16(u[4], u[5]); hi.w = pack_hi16(u[6], u[7]);
  lo.x = pack_hi16(l[0], l[1]); lo.y = pack_hi16(l[2], l[3]);
  lo.z = pack_hi16(l[4], l[5]); lo.w = pack_hi16(l[6], l[7]);
}

// ---------------------------------------------------------------------------
// Weight repack + f32 -> bf16 hi/lo planes (RNE; one-time). j = d*48 + k*16 + h.
__global__ void repack_w(const float* __restrict__ Wqkv, const float* __restrict__ Wtqkv,
                         const float* __restrict__ Wout,
                         u16* __restrict__ Wtq_hi, u16* __restrict__ Wtq_lo,
                         u16* __restrict__ Wk_hi,  u16* __restrict__ Wk_lo,
                         u16* __restrict__ Wv_hi,  u16* __restrict__ Woutb) {
  int r = blockIdx.x;              // 0..4095
  int part = r >> 10;
  int rr = r & 1023;
  int h = rr >> 6, d = rr & 63;
  const float* src;
  u16 *dh, *dl = nullptr;
  if (part == 0)      { src = Wtqkv + (size_t)(d * 48 + h) * 1024;      dh = Wtq_hi + (size_t)rr * 1024; dl = Wtq_lo + (size_t)rr * 1024; }
  else if (part == 1) { src = Wqkv  + (size_t)(d * 48 + 16 + h) * 1024; dh = Wk_hi  + (size_t)rr * 1024; dl = Wk_lo  + (size_t)rr * 1024; }
  else if (part == 2) { src = Wqkv  + (size_t)(d * 48 + 32 + h) * 1024; dh = Wv_hi  + (size_t)rr * 1024; }
  else                { src = Wout  + (size_t)rr * 1024;                dh = Woutb  + (size_t)rr * 1024; }
  int c = threadIdx.x * 4;
  f32x4 v = *(const f32x4*)&src[c];
  u32 hv[4], lv[4];
#pragma unroll
  for (int j = 0; j < 4; ++j) {
    u16 hb = f32_to_bf16(v[j]);
    hv[j] = hb;
    lv[j] = f32_to_bf16(v[j] - bf16_to_f32(hb));
  }
  uint2 ho; ho.x = hv[0] | (hv[1] << 16); ho.y = hv[2] | (hv[3] << 16);
  *(uint2*)&dh[c] = ho;
  if (dl) {
    uint2 lo; lo.x = lv[0] | (lv[1] << 16); lo.y = lv[2] | (lv[3] << 16);
    *(uint2*)&dl[c] = lo;
  }
}

// ---------------------------------------------------------------------------
// Fused projection GEMM v3: 64x128 tile, 48KB LDS, 3 blocks/CU.
// grid (512,3). Jobs 0/1: A = activations f32 (64 rows, split in-reg),
// B = weight hi/lo planes (128 rows). Job 2: A = Wv hi (64 rows),
// B = x f32 (128 rows, packed in-reg).
__global__ __launch_bounds__(256) __attribute__((amdgpu_waves_per_eu(3)))
void proj_fused(const float* __restrict__ x, const float* __restrict__ tx,
                const u16* __restrict__ Wtq_hi, const u16* __restrict__ Wtq_lo,
                const u16* __restrict__ Wk_hi,  const u16* __restrict__ Wk_lo,
                const u16* __restrict__ Wv_hi,
                u16* __restrict__ Qhi, u16* __restrict__ Qlo,
                u16* __restrict__ Khi, u16* __restrict__ Klo,
                u16* __restrict__ Vt, float qscale) {
  // 48KB carved per job:
  //  jobs 0/1: F[2][64][32]f32 @0 (16K) | H[2][128][32]u16 @16K (16K) | L @32K
  //  job 2:    F[2][128][32]f32 @0 (32K) | H[2][64][32]u16 @32K (8K)
  __shared__ __align__(16) char lds[49152];
  const int tid = threadIdx.x;
  const int wid = tid >> 6, lane = tid & 63;
  const int g = lane >> 4, l16 = lane & 15;
  const int job = blockIdx.y;
  const int tile = blockIdx.x;                 // 0..511
  const int wm = (wid & 1) * 32, wn = (wid >> 1) * 64;

  int m0, n0, N, frow0, hrow0;
  const float* Fsrc;
  const u16 *Hsrc;
  const u16 *Lsrc = nullptr;
  if (job == 0) {
    m0 = (tile >> 3) * 64; n0 = (tile & 7) * 128; N = 1024;
    Fsrc = tx; frow0 = m0; Hsrc = Wtq_hi; Lsrc = Wtq_lo; hrow0 = n0;
  } else if (job == 1) {
    m0 = (tile >> 3) * 64; n0 = (tile & 7) * 128; N = 1024;
    Fsrc = x; frow0 = m0; Hsrc = Wk_hi; Lsrc = Wk_lo; hrow0 = n0;
  } else {
    m0 = (tile >> 5) * 64; n0 = (tile & 31) * 128; N = 4096;
    Fsrc = x; frow0 = n0; Hsrc = Wv_hi; hrow0 = m0;
  }

  const int fstride = (job != 2) ? 8192 : 16384;   // F bytes per buffer
  char* const Fb0 = lds;
  char* const Hb0 = (job != 2) ? (lds + 16384) : (lds + 32768);
  const int hstride = (job != 2) ? 8192 : 4096;
  char* const Lb0 = lds + 32768;                   // jobs 0/1 only

  // DMA lane geometry. F granule swizzle: 8x16B granules per 128B row,
  // gran ^= row&7. H/L: 4x16B granules per 64B row, gran ^= (r^(r>>2))&3.
  const int lrow8 = lane >> 3;
  const int gf = (lane & 7) ^ lrow8;
  const int lrow4 = lane >> 2;
  const int gh = (lane & 3) ^ ((lrow4 ^ (lrow4 >> 2)) & 3);

  auto issue_chunk = [&](int k0, int p) {
    if (job != 2) {
      char* Fb = Fb0 + p * fstride;
      char* Hb = Hb0 + p * hstride;
      char* Lb = Lb0 + p * hstride;
#pragma unroll
      for (int t = 0; t < 2; ++t) {            // F: 64 rows, 8 rows/dma
        int rb = wid * 8 + t * 32;
        dma16(&Fsrc[(size_t)(frow0 + rb + lrow8) * 1024 + k0 + gf * 4], Fb + rb * 128);
      }
#pragma unroll
      for (int t = 0; t < 2; ++t) {            // H/L: 128 rows, 16 rows/dma
        int rb = wid * 16 + t * 64;
        size_t ro = (size_t)(hrow0 + rb + lrow4) * 1024 + k0 + gh * 8;
        dma16(&Hsrc[ro], Hb + rb * 64);
        dma16(&Lsrc[ro], Lb + rb * 64);
      }
    } else {
      char* Fb = Fb0 + p * fstride;
      char* Hb = Hb0 + p * hstride;
#pragma unroll
      for (int t = 0; t < 4; ++t) {            // F: 128 rows, 8 rows/dma
        int rb = wid * 8 + t * 32;
        dma16(&Fsrc[(size_t)(frow0 + rb + lrow8) * 1024 + k0 + gf * 4], Fb + rb * 128);
      }
      {                                         // H: 64 rows, 16 rows/dma
        int rb = wid * 16;
        dma16(&Hsrc[(size_t)(hrow0 + rb + lrow4) * 1024 + k0 + gh * 8], Hb + rb * 64);
      }
    }
  };

  f32x4 acc[2][4];
  const f32x4 zero4 = {0.f, 0.f, 0.f, 0.f};
#pragma unroll
  for (int i = 0; i < 2; ++i)
#pragma unroll
    for (int j = 0; j < 4; ++j) acc[i][j] = zero4;

  // read-side swizzles (F row&7 == l16&7; H/L row&15 == l16)
  const int sw8 = l16 & 7;
  const int sw4 = (l16 ^ (l16 >> 2)) & 3;

  issue_chunk(0, 0);

  for (int k0 = 0; k0 < 1024; k0 += 32) {
    const int p = (k0 >> 5) & 1;
    // Barrier's implicit vmcnt(0) drain: DMA into buf p (issued last step)
    // complete; all waves done reading buf p^1, so it's free for next DMA.
    __syncthreads();
    if (k0 + 32 < 1024) issue_chunk(k0 + 32, p ^ 1);

    char* Fb = Fb0 + p * fstride;
    char* Hb = Hb0 + p * hstride;
    if (job != 2) {
      char* Lb = Lb0 + p * hstride;
      short8 ah[2], al[2], bh4[4], bl4[4];
#pragma unroll
      for (int mi = 0; mi < 2; ++mi) {
        const int R = wm + mi * 16 + l16;
        uint4 u0 = *(const uint4*)(Fb + R * 128 + ((2 * g) ^ sw8) * 16);
        uint4 u1 = *(const uint4*)(Fb + R * 128 + ((2 * g + 1) ^ sw8) * 16);
        uint4 hi, lo;
        split8(u0, u1, hi, lo);
        ah[mi] = *(short8*)&hi;
        al[mi] = *(short8*)&lo;
      }
#pragma unroll
      for (int ni = 0; ni < 4; ++ni) {
        const int R = wn + ni * 16 + l16;
        bh4[ni] = *(const short8*)(Hb + R * 64 + (g ^ sw4) * 16);
        bl4[ni] = *(const short8*)(Lb + R * 64 + (g ^ sw4) * 16);
      }
#pragma unroll
      for (int mi = 0; mi < 2; ++mi)
#pragma unroll
        for (int ni = 0; ni < 4; ++ni) {
          acc[mi][ni] = __builtin_amdgcn_mfma_f32_16x16x32_bf16(ah[mi], bh4[ni], acc[mi][ni], 0, 0, 0);
          acc[mi][ni] = __builtin_amdgcn_mfma_f32_16x16x32_bf16(ah[mi], bl4[ni], acc[mi][ni], 0, 0, 0);
          acc[mi][ni] = __builtin_amdgcn_mfma_f32_16x16x32_bf16(al[mi], bh4[ni], acc[mi][ni], 0, 0, 0);
        }
    } else {
      short8 av[2], bx[4];
#pragma unroll
      for (int mi = 0; mi < 2; ++mi)
        av[mi] = *(const short8*)(Hb + (wm + mi * 16 + l16) * 64 + (g ^ sw4) * 16);
#pragma unroll
      for (int ni = 0; ni < 4; ++ni) {
        const int R = wn + ni * 16 + l16;
        uint4 u0 = *(const uint4*)(Fb + R * 128 + ((2 * g) ^ sw8) * 16);
        uint4 u1 = *(const uint4*)(Fb + R * 128 + ((2 * g + 1) ^ sw8) * 16);
        uint4 t = pack_bf16_8(u0, u1);
        bx[ni] = *(short8*)&t;
      }
#pragma unroll
      for (int mi = 0; mi < 2; ++mi)
#pragma unroll
        for (int ni = 0; ni < 4; ++ni)
          acc[mi][ni] = __builtin_amdgcn_mfma_f32_16x16x32_bf16(av[mi], bx[ni], acc[mi][ni], 0, 0, 0);
    }
  }

  u16* Chi = (job == 0) ? Qhi : ((job == 1) ? Khi : Vt);
  u16* Clo = (job == 0) ? Qlo : Klo;
  float scale = (job == 0) ? qscale : 1.0f;
#pragma unroll
  for (int mi = 0; mi < 2; ++mi)
#pragma unroll
    for (int ni = 0; ni < 4; ++ni) {
      int row = m0 + wm + mi * 16 + g * 4;
      int col = n0 + wn + ni * 16 + l16;
#pragma unroll
      for (int r = 0; r < 4; ++r) {
        float v = acc[mi][ni][r] * scale;
        size_t o = (size_t)(row + r) * N + col;
        u32 uv = __float_as_uint(v);
        if (job != 2) {
          Chi[o] = (u16)(uv >> 16);
          float lo = v - __uint_as_float(uv & 0xffff0000u);
          Clo[o] = (u16)(__float_as_uint(lo) >> 16);
        } else {
          Chi[o] = (u16)(uv >> 16);
        }
      }
    }
}

// ---------------------------------------------------------------------------
// Final projection (unchanged): C(f32) = A bf16 * B^T bf16.
__global__ __launch_bounds__(256) __attribute__((amdgpu_waves_per_eu(2, 4)))
void gemm_out(const u16* __restrict__ A, const u16* __restrict__ B,
              float* __restrict__ C, int M, int N, int K) {
  __shared__ __align__(16) u16 As[128][40];
  __shared__ __align__(16) u16 Bs[64][40];
  const int tid = threadIdx.x;
  const int wid = tid >> 6, lane = tid & 63;
  const int g = lane >> 4, l16 = lane & 15;
  const int m0 = blockIdx.y * 128, n0 = blockIdx.x * 64;
  const int wm = (wid & 1) * 64, wn = (wid >> 1) * 32;

  f32x4 acc[4][2];
  const f32x4 zero4 = {0.f, 0.f, 0.f, 0.f};
#pragma unroll
  for (int i = 0; i < 4; ++i)
#pragma unroll
    for (int j = 0; j < 2; ++j) acc[i][j] = zero4;

  uint4 pa[2], pb;
  const int rowA0 = tid >> 2, colA = (tid & 3) * 8;
  const int rowA1 = rowA0 + 64;
  const int rowB = tid >> 2, colB = (tid & 3) * 8;
  pa[0] = *(const uint4*)&A[(size_t)(m0 + rowA0) * K + colA];
  pa[1] = *(const uint4*)&A[(size_t)(m0 + rowA1) * K + colA];
  pb    = *(const uint4*)&B[(size_t)(n0 + rowB) * K + colB];

  for (int k0 = 0; k0 < K; k0 += 32) {
    __syncthreads();
    *(uint4*)&As[rowA0][colA] = pa[0];
    *(uint4*)&As[rowA1][colA] = pa[1];
    *(uint4*)&Bs[rowB][colB] = pb;
    __syncthreads();
    if (k0 + 32 < K) {
      pa[0] = *(const uint4*)&A[(size_t)(m0 + rowA0) * K + k0 + 32 + colA];
      pa[1] = *(const uint4*)&A[(size_t)(m0 + rowA1) * K + k0 + 32 + colA];
      pb    = *(const uint4*)&B[(size_t)(n0 + rowB) * K + k0 + 32 + colB];
    }
    short8 af[4], bfr[2];
#pragma unroll
    for (int mi = 0; mi < 4; ++mi)
      af[mi] = *(const short8*)&As[wm + mi * 16 + l16][g * 8];
#pragma unroll
    for (int ni = 0; ni < 2; ++ni)
      bfr[ni] = *(const short8*)&Bs[wn + ni * 16 + l16][g * 8];
#pragma unroll
    for (int mi = 0; mi < 4; ++mi)
#pragma unroll
      for (int ni = 0; ni < 2; ++ni)
        acc[mi][ni] = __builtin_amdgcn_mfma_f32_16x16x32_bf16(af[mi], bfr[ni], acc[mi][ni], 0, 0, 0);
  }
#pragma unroll
  for (int mi = 0; mi < 4; ++mi)
#pragma unroll
    for (int ni = 0; ni < 2; ++ni) {
      int row = m0 + wm + mi * 16 + g * 4;
      int col = n0 + wn + ni * 16 + l16;
#pragma unroll
      for (int r = 0; r < 4; ++r)
        C[(size_t)(row + r) * N + col] = acc[mi][ni][r];
    }
}

// ---------------------------------------------------------------------------
// Flash attention v10 (unchanged from r11): 8 waves x 16 q rows, swapped QK^T,
// in-register softmax with defer-max, __shfl P^T redistribution, PV = V^T.P^T.
__global__ __launch_bounds__(512)
void attn_fwd(const u16* __restrict__ Qhi, const u16* __restrict__ Qlo,
              const u16* __restrict__ Khi, const u16* __restrict__ Klo,
              const u16* __restrict__ Vt, u16* __restrict__ O) {
  const int blk = blockIdx.x;              // 512 blocks
  const int qb = blk & 15, bh = blk >> 4;
  const int h = bh & 15, b = bh >> 4;
  const int t0 = qb * 128;
  const int tid = threadIdx.x, wid = tid >> 6, lane = tid & 63;
  const int g = lane >> 4, l16 = lane & 15;
  const int par = g & 1;                   // group parity within 32-lane half
  const int hi2 = g >> 1;                  // which 32-lane half

  __shared__ __align__(16) u16 Ksh[2][64][64];   // keys x d (unpadded, swizzled)
  __shared__ __align__(16) u16 Ksl[2][64][64];
  __shared__ __align__(16) u16 Vs[2][64][64];    // d x keys (unpadded, swizzled)

  const int lrow = lane >> 3;              // 0..7
  const int lgc  = (lane & 7) ^ lrow;      // swizzled source granule
  const size_t kbase = (size_t)(b * 2048) * 1024 + h * 64;
  const size_t vbase = (size_t)(h * 64) * 4096 + b * 2048;

  auto issue_chunk = [&](int j0, int p) {
    const int row = wid * 8 + lrow;
    dma16(&Khi[kbase + (size_t)(j0 + row) * 1024 + lgc * 8], &Ksh[p][wid * 8][0]);
    dma16(&Klo[kbase + (size_t)(j0 + row) * 1024 + lgc * 8], &Ksl[p][wid * 8][0]);
    dma16(&Vt[vbase + (size_t)row * 4096 + j0 + lgc * 8],    &Vs[p][wid * 8][0]);
  };

  short8 qh[2], ql[2];
#pragma unroll
  for (int ks = 0; ks < 2; ++ks) {
    size_t qo = (size_t)(b * 2048 + t0 + wid * 16 + l16) * 1024
                + h * 64 + ks * 32 + g * 8;
    qh[ks] = *(const short8*)&Qhi[qo];
    ql[ks] = *(const short8*)&Qlo[qo];
  }

  float mrow = -1.0e30f;
  const f32x4 zero4 = {0.f, 0.f, 0.f, 0.f};
  f32x4 acc[5];                            // O^T quadrants; [4] = row-sum
#pragma unroll
  for (int dn = 0; dn < 5; ++dn) acc[dn] = zero4;

  short8 ones8;
#pragma unroll
  for (int j = 0; j < 8; ++j) ones8[j] = (short)0x3f80;   // bf16 1.0

  union PB { u32 w[4]; short8 v; };

  issue_chunk(0, 0);   // prologue DMA

  for (int i = 0; i < 32; ++i) {
    const int p = i & 1;
    __syncthreads();
    if (i < 31) issue_chunk((i + 1) * 64, 1 - p);

    f32x4 s[4];
#pragma unroll
    for (int n = 0; n < 4; ++n) s[n] = zero4;
#pragma unroll
    for (int ks = 0; ks < 2; ++ks)
#pragma unroll
      for (int n = 0; n < 4; ++n) {
        int col = (((ks * 4 + g) ^ (l16 & 7))) * 8;
        short8 kh = *(const short8*)&Ksh[p][n * 16 + l16][col];
        short8 kl = *(const short8*)&Ksl[p][n * 16 + l16][col];
        s[n] = __builtin_amdgcn_mfma_f32_16x16x32_bf16(kh, qh[ks], s[n], 0, 0, 0);
        s[n] = __builtin_amdgcn_mfma_f32_16x16x32_bf16(kh, ql[ks], s[n], 0, 0, 0);
        s[n] = __builtin_amdgcn_mfma_f32_16x16x32_bf16(kl, qh[ks], s[n], 0, 0, 0);
      }

    float cm = -1.0e30f;
#pragma unroll
    for (int n = 0; n < 4; ++n)
#pragma unroll
      for (int r = 0; r < 4; ++r) cm = fmaxf(cm, s[n][r]);
    cm = fmaxf(cm, __shfl_xor(cm, 16));
    cm = fmaxf(cm, __shfl_xor(cm, 32));
    if (!__all(cm <= mrow + 8.0f)) {
      float mnew = fmaxf(mrow, cm);
      float al = EXP2F(mrow - mnew);
      mrow = mnew;
#pragma unroll
      for (int dn = 0; dn < 5; ++dn)
#pragma unroll
        for (int r = 0; r < 4; ++r) acc[dn][r] *= al;
    }

    u32 pk[4][2];
#pragma unroll
    for (int n = 0; n < 4; ++n) {
      float p0 = EXP2F(s[n][0] - mrow);
      float p1 = EXP2F(s[n][1] - mrow);
      float p2 = EXP2F(s[n][2] - mrow);
      float p3 = EXP2F(s[n][3] - mrow);
      pk[n][0] = pack_hi16(__float_as_uint(p0), __float_as_uint(p1));
      pk[n][1] = pack_hi16(__float_as_uint(p2), __float_as_uint(p3));
    }
    PB pb[2];
#pragma unroll
    for (int ks2 = 0; ks2 < 2; ++ks2)
#pragma unroll
      for (int t = 0; t < 4; ++t) {
        int src = (((par << 1) | (t >> 1)) << 4) | l16;
        u32 w0 = (u32)__shfl((int)pk[2 * ks2][t & 1], src);
        u32 w1 = (u32)__shfl((int)pk[2 * ks2 + 1][t & 1], src);
        pb[ks2].w[t] = hi2 ? w1 : w0;
      }

#pragma unroll
    for (int ks2 = 0; ks2 < 2; ++ks2) {
#pragma unroll
      for (int dn = 0; dn < 4; ++dn) {
        int col = (((ks2 * 4 + g) ^ (l16 & 7))) * 8;
        short8 vb = *(const short8*)&Vs[p][dn * 16 + l16][col];
        acc[dn] = __builtin_amdgcn_mfma_f32_16x16x32_bf16(vb, pb[ks2].v, acc[dn], 0, 0, 0);
      }
      acc[4] = __builtin_amdgcn_mfma_f32_16x16x32_bf16(ones8, pb[ks2].v, acc[4], 0, 0, 0);
    }
  }

  float inv = 1.f / acc[4][0];
  int qrow = t0 + wid * 16 + l16;
  size_t base = (size_t)(b * 2048 + qrow) * 1024 + h * 64;
#pragma unroll
  for (int dn = 0; dn < 4; ++dn) {
    u32 o0 = pack_hi16(__float_as_uint(acc[dn][0] * inv),
                       __float_as_uint(acc[dn][1] * inv));
    u32 o1 = pack_hi16(__float_as_uint(acc[dn][2] * inv),
                       __float_as_uint(acc[dn][3] * inv));
    uint2 ov; ov.x = o0; ov.y = o1;
    *(uint2*)&O[base + dn * 16 + g * 4] = ov;
  }
}

// ---------------------------------------------------------------------------
extern "C" void kernel_launch(void* const* d_in, const int* in_sizes, int n_in,
                              void* d_out, int out_size, void* d_ws, size_t ws_size,
                              hipStream_t stream) {
  const float* x     = (const float*)d_in[0];
  const float* tx    = (const float*)d_in[1];
  const float* Wqkv  = (const float*)d_in[2];
  const float* Wtqkv = (const float*)d_in[3];
  const float* Wout  = (const float*)d_in[4];
  float* out = (float*)d_out;

  // workspace (peak 52 MB):
  //  0 Wtq_hi | 2 Wtq_lo | 4 Wk_hi | 6 Wk_lo | 8 Wv_hi | 10 Wout_b  (MB)
  //  12 Qhi 8 | 20 Qlo 8 | 28 Khi 8 | 36 Klo 8 | 44 Vt 8
  //  Ob (8MB) aliases 0-8 (weight planes dead after projections)
  char* ws = (char*)d_ws;
  const size_t MB = 1048576;
  u16* Wtq_hi = (u16*)(ws + 0 * MB);
  u16* Wtq_lo = (u16*)(ws + 2 * MB);
  u16* Wk_hi  = (u16*)(ws + 4 * MB);
  u16* Wk_lo  = (u16*)(ws + 6 * MB);
  u16* Wv_hi  = (u16*)(ws + 8 * MB);
  u16* Woutb  = (u16*)(ws + 10 * MB);
  u16* Qhi    = (u16*)(ws + 12 * MB);
  u16* Qlo    = (u16*)(ws + 20 * MB);
  u16* Khi    = (u16*)(ws + 28 * MB);
  u16* Klo    = (u16*)(ws + 36 * MB);
  u16* Vt     = (u16*)(ws + 44 * MB);
  u16* Ob     = (u16*)(ws + 0 * MB);
  if (ws_size < 52 * MB) return;

  const float QSCALE = 8.0f * 1.4426950408889634f;  // sqrt(d)=8, log2(e)

  repack_w<<<4096, 256, 0, stream>>>(Wqkv, Wtqkv, Wout,
                                     Wtq_hi, Wtq_lo, Wk_hi, Wk_lo, Wv_hi, Woutb);
  proj_fused<<<dim3(512, 3), 256, 0, stream>>>(x, tx, Wtq_hi, Wtq_lo, Wk_hi, Wk_lo,
                                               Wv_hi, Qhi, Qlo, Khi, Klo, Vt, QSCALE);
  attn_fwd<<<512, 512, 0, stream>>>(Qhi, Qlo, Khi, Klo, Vt, Ob);
  gemm_out<<<dim3(16, 32), 256, 0, stream>>>(Ob, Woutb, out, 4096, 1024, 1024);
}